// Round 21
// baseline (93.662 us; speedup 1.0000x reference)
//
#include <hip/hip_runtime.h>
#include <math.h>

#define S_LEN 2048
#define NHEADS 16
#define KVH 4

typedef __attribute__((ext_vector_type(8))) _Float16 half8;
typedef __attribute__((ext_vector_type(4))) _Float16 half4;
typedef __attribute__((ext_vector_type(2))) __fp16 fp16x2;   // cvt_pkrtz return type
typedef __attribute__((ext_vector_type(4))) float f32x4;

// async global->LDS, 16B per lane. LDS dest = wave-uniform base + lane*16.
__device__ inline void gld16(const void* g, void* l) {
  __builtin_amdgcn_global_load_lds(
      (const __attribute__((address_space(1))) unsigned int*)g,
      (__attribute__((address_space(3))) unsigned int*)l, 16, 0, 0);
}

// ---------------- fused setup: transposes + costab + gates(ag,veg) + x f32->f16 --------
// blocks [0,640): transpose wq/wk/wv/wo (f32 -> f16^T)
// blocks [640,768): costab[s][i] = (cos,sin)(s * 1024^(-i/16)), s<2048, i<16
// blocks [768,1024): ag[row][n] = 2*sigmoid(x[row,:12] @ attn_gate[:,n]);
//                    veg4[row][m] = velam*2*sigmoid(x[row,:12] @ ve_gate[:,m]) (m<4)
// blocks [1024,2048): xh = (f16)x, 16 elems/thread
__global__ __launch_bounds__(256) void setup_fused(
    const float* __restrict__ wq, const float* __restrict__ wk,
    const float* __restrict__ wv, const float* __restrict__ wo,
    const float* __restrict__ x, const float* __restrict__ attn_gate,
    const float* __restrict__ ve_gate, const float* __restrict__ velam,
    _Float16* __restrict__ wqkvT, _Float16* __restrict__ woT,
    float2* __restrict__ costab, float* __restrict__ ag,
    float* __restrict__ veg4, _Float16* __restrict__ xh)
{
  const int t = threadIdx.x;
  int L = blockIdx.x;

  if (L >= 1024) {          // ---- x cast ----
    const size_t i = ((size_t)(L - 1024) * 256 + t) * 16;
    #pragma unroll
    for (int c = 0; c < 2; c++) {
      float4 f0 = *(const float4*)(x + i + c * 8);
      float4 f1 = *(const float4*)(x + i + c * 8 + 4);
      half8 h;
      h[0] = (_Float16)f0.x; h[1] = (_Float16)f0.y; h[2] = (_Float16)f0.z; h[3] = (_Float16)f0.w;
      h[4] = (_Float16)f1.x; h[5] = (_Float16)f1.y; h[6] = (_Float16)f1.z; h[7] = (_Float16)f1.w;
      *(half8*)(xh + i + c * 8) = h;
    }
    return;
  }
  if (L >= 768) {           // ---- attn gates + value-embed gates ----
    const int row = (L - 768) * 16 + (t >> 4);
    const int n = t & 15;
    float z = 0.f;
    #pragma unroll
    for (int i = 0; i < 12; ++i) z += x[(size_t)row * 1024 + i] * attn_gate[i * NHEADS + n];
    ag[(size_t)row * NHEADS + n] = 2.f / (1.f + __expf(-z));
    if (n < KVH) {
      float z2 = 0.f;
      #pragma unroll
      for (int i = 0; i < 12; ++i) z2 += x[(size_t)row * 1024 + i] * ve_gate[i * KVH + n];
      veg4[(size_t)row * KVH + n] = velam[0] * 2.f / (1.f + __expf(-z2));
    }
    return;
  }
  if (L >= 640) {           // ---- cos/sin table ----
    const int gi = (L - 640) * 256 + t;      // 0..32767
    const int s = gi >> 4, i = gi & 15;
    const float ang = (float)s * exp2f(-0.625f * (float)i);
    float c, sn;
    sincosf(ang, &sn, &c);
    costab[gi] = make_float2(c, sn);
    return;
  }

  // ---- weight transpose + f32->f16 ----
  const float* in; _Float16* out; int C, ct, rt;
  if (L < 256)      { in = wq; out = wqkvT;                       C = 1024; ct = (L & 15) * 64; rt = (L >> 4) * 64; }
  else if (L < 320) { L -= 256; in = wk; out = wqkvT + (size_t)1024 * 1024; C = 256; ct = (L & 3) * 64; rt = (L >> 2) * 64; }
  else if (L < 384) { L -= 320; in = wv; out = wqkvT + (size_t)1280 * 1024; C = 256; ct = (L & 3) * 64; rt = (L >> 2) * 64; }
  else              { L -= 384; in = wo; out = woT;               C = 1024; ct = (L & 15) * 64; rt = (L >> 4) * 64; }

  __shared__ float Ls[64][65];
  {
    const int r = t >> 2, cs = (t & 3) << 4;
    const float* src = in + (size_t)(rt + r) * C + ct + cs;
    #pragma unroll
    for (int j = 0; j < 16; j += 4) {
      float4 v = *(const float4*)(src + j);
      Ls[r][cs + j] = v.x; Ls[r][cs + j + 1] = v.y;
      Ls[r][cs + j + 2] = v.z; Ls[r][cs + j + 3] = v.w;
    }
  }
  __syncthreads();
  {
    const int c = t >> 2, rs = (t & 3) << 4;
    half8 h0, h1;
    #pragma unroll
    for (int j = 0; j < 8; j++) h0[j] = (_Float16)Ls[rs + j][c];
    #pragma unroll
    for (int j = 0; j < 8; j++) h1[j] = (_Float16)Ls[rs + 8 + j][c];
    _Float16* dst = out + (size_t)(ct + c) * 1024 + rt + rs;
    *(half8*)dst = h0;
    *(half8*)(dst + 8) = h1;
  }
}

// ---------------- MFMA GEMM: C[M][N] = A[M][K] @ BT[N][K]^T, f16 inputs ----------------
// 64x128 tile, BK=64, 4 waves (2x2, each 32x64), dbuf LDS 48KB, ONE barrier per
// 64-K step. Row = 128B, 8x16B slots, slot XOR-swizzled by (row&7); src pre-swizzled.
// EPI (QKV projection): q/k heads get fused qk-norm + RoPE + q-scale; v heads get
// value-embed MIX + TRANSPOSED store directly into vT[64 d][S], skipping qkv.
template<typename OUT_T, bool EPI>
__global__ __launch_bounds__(256) void gemm_k(
    const _Float16* __restrict__ A, const _Float16* __restrict__ BT,
    OUT_T* __restrict__ C, int M, int N, int K, int lda,
    const float2* __restrict__ costab, const int* __restrict__ token_ids,
    const float* __restrict__ ve_embed, const float* __restrict__ veg4,
    const float* __restrict__ vlam, _Float16* __restrict__ vT)
{
  // LDS map (48KB): A buf0 [0,8K) buf1 [8K,16K); B buf0 [16K,32K) buf1 [32K,48K)
  __shared__ _Float16 lds[24576];
  const int t = threadIdx.x;
  const int w = t >> 6, l = t & 63;
  const int lg = l >> 4, ll = l & 15;
  const int bm = blockIdx.y * 64, bn = blockIdx.x * 128;
  const int wr = (w >> 1) * 32, wc = (w & 1) * 64;
  const int srow = l >> 3, sslot = l & 7;

  f32x4 acc[2][4] = {};

  auto stage = [&](int k0, int buf) {
    char* Ab = (char*)lds + buf * 8192;
    char* Bb = (char*)lds + 16384 + buf * 16384;
    #pragma unroll
    for (int i = 0; i < 2; i++) {
      const int row = w * 16 + i * 8 + srow;
      gld16(A + (size_t)(bm + row) * lda + k0 + ((sslot ^ (row & 7)) << 3),
            Ab + w * 2048 + i * 1024);
    }
    #pragma unroll
    for (int i = 0; i < 4; i++) {
      const int row = w * 32 + i * 8 + srow;
      gld16(BT + (size_t)(bn + row) * K + k0 + ((sslot ^ (row & 7)) << 3),
            Bb + w * 4096 + i * 1024);
    }
  };

  stage(0, 0);
  __syncthreads();

  int buf = 0;
  for (int k0 = 0; k0 < K; k0 += 64) {
    if (k0 + 64 < K) stage(k0 + 64, buf ^ 1);   // overlap next-step loads with MFMAs

    const char* Ab = (const char*)lds + buf * 8192;
    const char* Bb = (const char*)lds + 16384 + buf * 16384;
    half8 af[2][2], bfr[2][4];
    #pragma unroll
    for (int mt = 0; mt < 2; mt++) {
      const int row = wr + mt * 16 + ll;
      #pragma unroll
      for (int s = 0; s < 2; s++)
        af[mt][s] = *(const half8*)(Ab + row * 128 + (((4 * s + lg) ^ (row & 7)) << 4));
    }
    #pragma unroll
    for (int nt = 0; nt < 4; nt++) {
      const int row = wc + nt * 16 + ll;
      #pragma unroll
      for (int s = 0; s < 2; s++)
        bfr[s][nt] = *(const half8*)(Bb + row * 128 + (((4 * s + lg) ^ (row & 7)) << 4));
    }
    __builtin_amdgcn_s_setprio(1);
    #pragma unroll
    for (int s = 0; s < 2; s++)
      #pragma unroll
      for (int mt = 0; mt < 2; mt++)
        #pragma unroll
        for (int nt = 0; nt < 4; nt++)
          acc[mt][nt] = __builtin_amdgcn_mfma_f32_16x16x32_f16(af[mt][s], bfr[s][nt], acc[mt][nt], 0, 0, 0);
    __builtin_amdgcn_s_setprio(0);

    __syncthreads();   // drains this step's gld16s; guards buffer reuse
    buf ^= 1;
  }

  // D layout: col = lane&15, row = (lane>>4)*4 + reg
  if constexpr (EPI) {
    const int col0 = bn + wc;
    const int head = col0 >> 6;
    if (head >= 20) {
      // ---- v heads: mix with value-embedding, store TRANSPOSED into vT ----
      const int mloc = head - 20;
      const int bq = bm >> 11;                 // batch (rows 0..2047 -> b=0)
      const int vbm = bq * KVH + mloc;
      const int sl0 = bm - bq * S_LEN;         // tile's local s of row 0
      const float vl = vlam[0];
      #pragma unroll
      for (int mt = 0; mt < 2; mt++) {
        const int s_base = sl0 + wr + mt * 16 + lg * 4;   // local s for r=0
        int   tok[4];
        float vg[4];
        #pragma unroll
        for (int r = 0; r < 4; r++) {
          const size_t grow = (size_t)bq * S_LEN + s_base + r;
          tok[r] = token_ids[grow];
          vg[r]  = veg4[grow * KVH + mloc];
        }
        #pragma unroll
        for (int nt = 0; nt < 4; nt++) {
          const int d = nt * 16 + ll;          // dim within head (col0 == head*64)
          half4 o4;
          #pragma unroll
          for (int r = 0; r < 4; r++) {
            const float e = ve_embed[(size_t)tok[r] * 256 + mloc * 64 + d];
            o4[r] = (_Float16)(vl * acc[mt][nt][r] + vg[r] * e);
          }
          *(half4*)(vT + ((size_t)vbm * 64 + d) * S_LEN + s_base) = o4;
        }
      }
    } else {
      // ---- q/k heads: qk-norm + RoPE (+ q-scale) ----
      const float qs = (head < 16) ? 0.18033688f : 1.0f;  // 1/sqrt(HD)*log2e into q
      #pragma unroll
      for (int mt = 0; mt < 2; mt++) {
        float ss[4];
        #pragma unroll
        for (int r = 0; r < 4; r++)
          ss[r] = acc[mt][0][r] * acc[mt][0][r] + acc[mt][1][r] * acc[mt][1][r]
                + acc[mt][2][r] * acc[mt][2][r] + acc[mt][3][r] * acc[mt][3][r];
        #pragma unroll
        for (int mi = 0; mi < 4; mi++) {
          const int msk = 1 << mi;   // 1,2,4,8: stays within the 16-lane row group
          #pragma unroll
          for (int r = 0; r < 4; r++) ss[r] += __shfl_xor(ss[r], msk);
        }
        #pragma unroll
        for (int r = 0; r < 4; r++) {
          const size_t row = (size_t)bm + wr + mt * 16 + lg * 4 + r;
          const float inv = rsqrtf(ss[r] * (1.0f / 64.0f) + 1e-6f) * qs;
          const float2 cs2 = costab[(row & (S_LEN - 1)) * 16 + ll];
          const float a0 = acc[mt][0][r] * inv, a1 = acc[mt][1][r] * inv;
          C[row * N + col0 +      ll] = (OUT_T)(a0 * cs2.x - a1 * cs2.y);
          C[row * N + col0 + 16 + ll] = (OUT_T)(a1 * cs2.x + a0 * cs2.y);
          C[row * N + col0 + 32 + ll] = (OUT_T)(acc[mt][2][r] * inv);
          C[row * N + col0 + 48 + ll] = (OUT_T)(acc[mt][3][r] * inv);
        }
      }
    }
  } else {
    #pragma unroll
    for (int mt = 0; mt < 2; mt++) {
      #pragma unroll
      for (int r = 0; r < 4; r++) {
        const size_t row = (size_t)bm + wr + mt * 16 + lg * 4 + r;
        #pragma unroll
        for (int nt = 0; nt < 4; nt++) {
          const int col = bn + wc + nt * 16 + ll;
          if constexpr (sizeof(OUT_T) == 2) C[row * N + col] = (OUT_T)(_Float16)acc[mt][nt][r];
          else                              C[row * N + col] = acc[mt][nt][r];
        }
      }
    }
  }
}

// ---------------- MFMA flash attention (causal, GQA), FIXED-MAX, UNIFORM PAIRS --------
// 512 blocks x 256 threads. Block (b, n, u) processes the COMPLEMENTARY q-tile pair
// (31-u, u) sequentially: (32-u) + (u+1) = 33 tile-steps per block, constant ->
// makespan is assignment-independent (fixes the measured 23% occupancy / 1:32
// per-block work spread). 2 blocks/CU always resident (LDS 40KB allows 4).
// Inner loop identical to r20: 2q x 2k wave split, KVBLK=64 dbuf, fixed max M=11.6
// in MFMA C-init, l via ones-column MFMA, cvt_pkrtz pack, cross-k-half LDS reduction.
__global__ __launch_bounds__(256) void attn_mfma(
    _Float16* __restrict__ qkv, const _Float16* __restrict__ vT,
    const float* __restrict__ ag)
{
  const int L = blockIdx.x;
  const int n = L & 15;
  const int b = (L >> 4) & 1;
  const int u = L >> 5;                 // 0..15
  const int m = n >> 2;

  const int t = threadIdx.x, w = t >> 6, l = t & 63;
  const int lg = l >> 4, ll = l & 15;
  const int g  = w & 1;                 // q-group (32 rows)
  const int kh = w >> 1;                // k-half (32 cols of each tile)

  // LDS map (40 KB): [0,16K) = K buf0/1, [16K,32K) = V buf0/1, [32K,40K) = Ps
  __shared__ _Float16 lds[20480];

  half8 ones;
  #pragma unroll
  for (int i = 0; i < 8; i++) ones[i] = (_Float16)1.0f;

  const int srow = l >> 3, sslot = l & 7;

  auto stage = [&](int kt, int buf) {
    #pragma unroll
    for (int i = 0; i < 2; i++) {
      const int kr = w * 16 + i * 8 + srow;
      const size_t kg = ((size_t)(b * S_LEN + kt * 64 + kr)) * 1536 + 1024 + m * 64
                        + ((sslot ^ (kr & 7)) << 3);
      gld16(qkv + kg, (char*)lds + buf * 8192 + w * 2048 + i * 1024);
      const int vr = w * 16 + i * 8 + srow;
      const size_t vg = ((size_t)((b * KVH + m) * 64 + vr)) * S_LEN + kt * 64
                        + ((sslot ^ (vr & 7)) << 3);
      gld16(vT + vg, (char*)lds + 16384 + buf * 8192 + w * 2048 + i * 1024);
    }
  };

  for (int phase = 0; phase < 2; phase++) {
    const int qt = phase ? u : 31 - u;  // pair (31-u, u): 33 tile-steps total

    const int qbl = qt * 64 + g * 32;   // sequence-local first q row of this wave
    const size_t qrow_g = (size_t)(b * S_LEN) + qbl;

    half8 qa[2][2];
    #pragma unroll
    for (int qf = 0; qf < 2; qf++)
      #pragma unroll
      for (int s = 0; s < 2; s++)
        qa[qf][s] = *(const half8*)(qkv + (qrow_g + qf * 16 + ll) * 1536 + n * 64 + s * 32 + lg * 8);

    float agr[2][4];
    if (kh == 0) {   // only the k-half-0 waves do the final write
      #pragma unroll
      for (int qf = 0; qf < 2; qf++)
        #pragma unroll
        for (int r = 0; r < 4; r++)
          agr[qf][r] = ag[(qrow_g + qf * 16 + lg * 4 + r) * NHEADS + n];
    }

    f32x4 o[2][4] = {};
    f32x4 ol[2] = {};                   // l via ones-column MFMA, per q-frag

    stage(0, 0);
    __syncthreads();

    for (int kt = 0; kt <= qt; kt++) {
      const int cur = kt & 1;
      if (kt < qt) stage(kt + 1, cur ^ 1);   // hide next tile's latency under compute

      const char* Ksb = (const char*)lds + cur * 8192;
      const char* Vsb = (const char*)lds + 16384 + cur * 8192;
      char* Psb = (char*)lds + 32768;

      // QK^T (swapped), C pre-seeded with the fixed max: sc = K.Q - 11.6.
      f32x4 sc[2][2];
      #pragma unroll
      for (int qf = 0; qf < 2; qf++)
        #pragma unroll
        for (int kf = 0; kf < 2; kf++) {
          sc[qf][kf][0] = -11.6f; sc[qf][kf][1] = -11.6f;
          sc[qf][kf][2] = -11.6f; sc[qf][kf][3] = -11.6f;
        }
      __builtin_amdgcn_s_setprio(1);
      #pragma unroll
      for (int s = 0; s < 2; s++)
        #pragma unroll
        for (int kf = 0; kf < 2; kf++) {
          const int krow = kh * 32 + kf * 16 + ll;
          const half8 kb = *(const half8*)(Ksb + krow * 128
                            + (((4 * s + lg) ^ (krow & 7)) << 4));
          sc[0][kf] = __builtin_amdgcn_mfma_f32_16x16x32_f16(kb, qa[0][s], sc[0][kf], 0, 0, 0);
          sc[1][kf] = __builtin_amdgcn_mfma_f32_16x16x32_f16(kb, qa[1][s], sc[1][kf], 0, 0, 0);
        }
      __builtin_amdgcn_s_setprio(0);

      if (kt == qt) {   // diagonal tile: causal mask (k > q -> -inf)
        #pragma unroll
        for (int qf = 0; qf < 2; qf++) {
          const int qg = qbl + qf * 16 + ll;
          #pragma unroll
          for (int kf = 0; kf < 2; kf++)
            #pragma unroll
            for (int r = 0; r < 4; r++)
              if (kt * 64 + kh * 32 + kf * 16 + 4 * lg + r > qg) sc[qf][kf][r] = -1e30f;
        }
      }

      // P = exp2(sc); packed f16 cvt into this wave's slots of Ps[64 q][64 k]
      #pragma unroll
      for (int qf = 0; qf < 2; qf++) {
        const int q_loc = g * 32 + qf * 16 + ll;
        #pragma unroll
        for (int kf = 0; kf < 2; kf++) {
          union { fp16x2 h2[2]; half4 h4; } P;
          P.h2[0] = __builtin_amdgcn_cvt_pkrtz(exp2f(sc[qf][kf][0]), exp2f(sc[qf][kf][1]));
          P.h2[1] = __builtin_amdgcn_cvt_pkrtz(exp2f(sc[qf][kf][2]), exp2f(sc[qf][kf][3]));
          const int slot = (4 * kh + 2 * kf + (lg >> 1)) ^ (q_loc & 7);
          *(half4*)(Psb + q_loc * 128 + slot * 16 + (lg & 1) * 8) = P.h4;
        }
      }

      // PV + l-by-ones over this wave's 32-k window (wave-local Ps, in-order per wave)
      __builtin_amdgcn_s_setprio(1);
      {
        half8 pa[2];
        #pragma unroll
        for (int qf = 0; qf < 2; qf++) {
          const int prow = g * 32 + qf * 16 + ll;
          pa[qf] = *(const half8*)(Psb + prow * 128 + (((4 * kh + lg) ^ (prow & 7)) << 4));
        }
        ol[0] = __builtin_amdgcn_mfma_f32_16x16x32_f16(pa[0], ones, ol[0], 0, 0, 0);
        ol[1] = __builtin_amdgcn_mfma_f32_16x16x32_f16(pa[1], ones, ol[1], 0, 0, 0);
        #pragma unroll
        for (int df = 0; df < 4; df++) {
          const int vrow = df * 16 + ll;
          const half8 vb = *(const half8*)(Vsb + vrow * 128
                            + (((4 * kh + lg) ^ (vrow & 7)) << 4));
          o[0][df] = __builtin_amdgcn_mfma_f32_16x16x32_f16(pa[0], vb, o[0][df], 0, 0, 0);
          o[1][df] = __builtin_amdgcn_mfma_f32_16x16x32_f16(pa[1], vb, o[1][df], 0, 0, 0);
        }
      }
      __builtin_amdgcn_s_setprio(0);

      __syncthreads();   // drains this wave's stage issues; guards buffer reuse
    }

    // ---- cross-k-half reduction through the now-dead K/V buffer LDS ----
    // kh=1 waves deposit partial (o, ol); after one barrier kh=0 waves add + write.
    char* red = (char*)lds;   // [0,16K): o partials f32[2 g][32 q][64 d]; +16K: ol
    if (kh == 1) {
      #pragma unroll
      for (int qf = 0; qf < 2; qf++) {
        #pragma unroll
        for (int df = 0; df < 4; df++)
          #pragma unroll
          for (int r = 0; r < 4; r++)
            *(float*)(red + g * 8192 + (qf * 16 + lg * 4 + r) * 256 + (df * 16 + ll) * 4)
                = o[qf][df][r];
        if (ll == 0)
          #pragma unroll
          for (int r = 0; r < 4; r++)
            *(float*)(red + 16384 + g * 128 + (qf * 16 + lg * 4 + r) * 4) = ol[qf][r];
      }
    }
    __syncthreads();
    if (kh == 0) {
      #pragma unroll
      for (int qf = 0; qf < 2; qf++)
        #pragma unroll
        for (int r = 0; r < 4; r++) {
          const int qloc32 = qf * 16 + lg * 4 + r;
          const float lsum = ol[qf][r] + *(const float*)(red + 16384 + g * 128 + qloc32 * 4);
          const size_t qrow = qrow_g + qf * 16 + lg * 4 + r;
          const float scale = agr[qf][r] / lsum;
          #pragma unroll
          for (int df = 0; df < 4; df++) {
            const float ov = o[qf][df][r]
                + *(const float*)(red + g * 8192 + qloc32 * 256 + (df * 16 + ll) * 4);
            qkv[qrow * 1536 + n * 64 + df * 16 + ll] = (_Float16)(ov * scale);
          }
        }
    }
    __syncthreads();   // epilogue reads of `red` drain before next phase's staging
  }
}

extern "C" void kernel_launch(void* const* d_in, const int* in_sizes, int n_in,
                              void* d_out, int out_size, void* d_ws, size_t ws_size,
                              hipStream_t stream) {
  const float* x         = (const float*)d_in[0];
  const int*   token_ids = (const int*)d_in[1];
  // d_in[2] = mask (causal, analytic) — unused
  const float* w_q       = (const float*)d_in[3];
  const float* w_k       = (const float*)d_in[4];
  const float* w_v       = (const float*)d_in[5];
  const float* w_o       = (const float*)d_in[6];
  const float* ve_embed  = (const float*)d_in[7];
  const float* vlam      = (const float*)d_in[8];
  const float* velam     = (const float*)d_in[9];
  const float* ve_gate   = (const float*)d_in[10];
  const float* attn_gate = (const float*)d_in[11];
  float* out = (float*)d_out;

  // workspace carve-up (~20.3 MB)
  char* p = (char*)d_ws;
  _Float16* wqkvT = (_Float16*)p; p += (size_t)1536 * 1024 * 2;    // [wq|wk|wv]^T
  _Float16* woT   = (_Float16*)p; p += (size_t)1024 * 1024 * 2;
  _Float16* qkv   = (_Float16*)p; p += (size_t)4096 * 1536 * 2;    // [B*S][q1024|k256|v-dead]
  _Float16* vTb   = (_Float16*)p; p += (size_t)8 * 64 * S_LEN * 2; // [B*M][64][S]
  float*    ag    = (float*)p;    p += (size_t)4096 * NHEADS * 4;
  float*    veg4  = (float*)p;    p += (size_t)4096 * KVH * 4;     // velam*2*sigmoid(..)

  // scratch aliased into d_out (16.8 MB, dead until final GEMM overwrites it):
  // xh = x as f16 at [0, 8.4MB); costab (256 KB) at [12MB, 12.25MB)
  _Float16* xh = (_Float16*)d_out;
  float2* costab = (float2*)((char*)d_out + (size_t)12 * 1024 * 1024);

  dim3 blk(256);
  setup_fused<<<dim3(2048), blk, 0, stream>>>(w_q, w_k, w_v, w_o, x, attn_gate,
                                              ve_gate, velam,
                                              wqkvT, woT, costab, ag, veg4, xh);

  gemm_k<_Float16, true><<<dim3(12, 64), blk, 0, stream>>>(
      xh, wqkvT, qkv, 4096, 1536, 1024, 1024,
      costab, token_ids, ve_embed, veg4, vlam, vTb);

  attn_mfma<<<dim3(512), blk, 0, stream>>>(qkv, vTb, ag);

  gemm_k<float, false><<<dim3(8, 64), blk, 0, stream>>>(
      qkv, woT, out, 4096, 1024, 1024, 1536,
      nullptr, nullptr, nullptr, nullptr, nullptr, nullptr);
}

// Round 22
// 89.357 us; speedup vs baseline: 1.0482x; 1.0482x over previous
//
#include <hip/hip_runtime.h>
#include <math.h>

#define S_LEN 2048
#define NHEADS 16
#define KVH 4

typedef __attribute__((ext_vector_type(8))) _Float16 half8;
typedef __attribute__((ext_vector_type(4))) _Float16 half4;
typedef __attribute__((ext_vector_type(2))) __fp16 fp16x2;   // cvt_pkrtz return type
typedef __attribute__((ext_vector_type(4))) float f32x4;

// async global->LDS, 16B per lane. LDS dest = wave-uniform base + lane*16.
__device__ inline void gld16(const void* g, void* l) {
  __builtin_amdgcn_global_load_lds(
      (const __attribute__((address_space(1))) unsigned int*)g,
      (__attribute__((address_space(3))) unsigned int*)l, 16, 0, 0);
}

// ---------------- fused setup: transposes + costab + gates(ag,veg) + x f32->f16 --------
// blocks [0,640): transpose wq/wk/wv/wo (f32 -> f16^T)
// blocks [640,768): costab[s][i] = (cos,sin)(s * 1024^(-i/16)), s<2048, i<16
// blocks [768,1024): ag[row][n] = 2*sigmoid(x[row,:12] @ attn_gate[:,n]);
//                    veg4[row][m] = velam*2*sigmoid(x[row,:12] @ ve_gate[:,m]) (m<4)
// blocks [1024,2048): xh = (f16)x, 16 elems/thread
__global__ __launch_bounds__(256) void setup_fused(
    const float* __restrict__ wq, const float* __restrict__ wk,
    const float* __restrict__ wv, const float* __restrict__ wo,
    const float* __restrict__ x, const float* __restrict__ attn_gate,
    const float* __restrict__ ve_gate, const float* __restrict__ velam,
    _Float16* __restrict__ wqkvT, _Float16* __restrict__ woT,
    float2* __restrict__ costab, float* __restrict__ ag,
    float* __restrict__ veg4, _Float16* __restrict__ xh)
{
  const int t = threadIdx.x;
  int L = blockIdx.x;

  if (L >= 1024) {          // ---- x cast ----
    const size_t i = ((size_t)(L - 1024) * 256 + t) * 16;
    #pragma unroll
    for (int c = 0; c < 2; c++) {
      float4 f0 = *(const float4*)(x + i + c * 8);
      float4 f1 = *(const float4*)(x + i + c * 8 + 4);
      half8 h;
      h[0] = (_Float16)f0.x; h[1] = (_Float16)f0.y; h[2] = (_Float16)f0.z; h[3] = (_Float16)f0.w;
      h[4] = (_Float16)f1.x; h[5] = (_Float16)f1.y; h[6] = (_Float16)f1.z; h[7] = (_Float16)f1.w;
      *(half8*)(xh + i + c * 8) = h;
    }
    return;
  }
  if (L >= 768) {           // ---- attn gates + value-embed gates ----
    const int row = (L - 768) * 16 + (t >> 4);
    const int n = t & 15;
    float z = 0.f;
    #pragma unroll
    for (int i = 0; i < 12; ++i) z += x[(size_t)row * 1024 + i] * attn_gate[i * NHEADS + n];
    ag[(size_t)row * NHEADS + n] = 2.f / (1.f + __expf(-z));
    if (n < KVH) {
      float z2 = 0.f;
      #pragma unroll
      for (int i = 0; i < 12; ++i) z2 += x[(size_t)row * 1024 + i] * ve_gate[i * KVH + n];
      veg4[(size_t)row * KVH + n] = velam[0] * 2.f / (1.f + __expf(-z2));
    }
    return;
  }
  if (L >= 640) {           // ---- cos/sin table ----
    const int gi = (L - 640) * 256 + t;      // 0..32767
    const int s = gi >> 4, i = gi & 15;
    const float ang = (float)s * exp2f(-0.625f * (float)i);
    float c, sn;
    sincosf(ang, &sn, &c);
    costab[gi] = make_float2(c, sn);
    return;
  }

  // ---- weight transpose + f32->f16 ----
  const float* in; _Float16* out; int C, ct, rt;
  if (L < 256)      { in = wq; out = wqkvT;                       C = 1024; ct = (L & 15) * 64; rt = (L >> 4) * 64; }
  else if (L < 320) { L -= 256; in = wk; out = wqkvT + (size_t)1024 * 1024; C = 256; ct = (L & 3) * 64; rt = (L >> 2) * 64; }
  else if (L < 384) { L -= 320; in = wv; out = wqkvT + (size_t)1280 * 1024; C = 256; ct = (L & 3) * 64; rt = (L >> 2) * 64; }
  else              { L -= 384; in = wo; out = woT;               C = 1024; ct = (L & 15) * 64; rt = (L >> 4) * 64; }

  __shared__ float Ls[64][65];
  {
    const int r = t >> 2, cs = (t & 3) << 4;
    const float* src = in + (size_t)(rt + r) * C + ct + cs;
    #pragma unroll
    for (int j = 0; j < 16; j += 4) {
      float4 v = *(const float4*)(src + j);
      Ls[r][cs + j] = v.x; Ls[r][cs + j + 1] = v.y;
      Ls[r][cs + j + 2] = v.z; Ls[r][cs + j + 3] = v.w;
    }
  }
  __syncthreads();
  {
    const int c = t >> 2, rs = (t & 3) << 4;
    half8 h0, h1;
    #pragma unroll
    for (int j = 0; j < 8; j++) h0[j] = (_Float16)Ls[rs + j][c];
    #pragma unroll
    for (int j = 0; j < 8; j++) h1[j] = (_Float16)Ls[rs + 8 + j][c];
    _Float16* dst = out + (size_t)(ct + c) * 1024 + rt + rs;
    *(half8*)dst = h0;
    *(half8*)(dst + 8) = h1;
  }
}

// ---------------- MFMA GEMM: C[M][N] = A[M][K] @ BT[N][K]^T, f16 inputs ----------------
// 64x128 tile, BK=64, 4 waves (2x2, each 32x64), dbuf LDS 48KB, ONE barrier per
// 64-K step. Row = 128B, 8x16B slots, slot XOR-swizzled by (row&7); src pre-swizzled.
// EPI (QKV projection): q/k heads get fused qk-norm + RoPE + q-scale; v heads get
// value-embed MIX + TRANSPOSED store directly into vT[64 d][S], skipping qkv.
template<typename OUT_T, bool EPI>
__global__ __launch_bounds__(256) void gemm_k(
    const _Float16* __restrict__ A, const _Float16* __restrict__ BT,
    OUT_T* __restrict__ C, int M, int N, int K, int lda,
    const float2* __restrict__ costab, const int* __restrict__ token_ids,
    const float* __restrict__ ve_embed, const float* __restrict__ veg4,
    const float* __restrict__ vlam, _Float16* __restrict__ vT)
{
  // LDS map (48KB): A buf0 [0,8K) buf1 [8K,16K); B buf0 [16K,32K) buf1 [32K,48K)
  __shared__ _Float16 lds[24576];
  const int t = threadIdx.x;
  const int w = t >> 6, l = t & 63;
  const int lg = l >> 4, ll = l & 15;
  const int bm = blockIdx.y * 64, bn = blockIdx.x * 128;
  const int wr = (w >> 1) * 32, wc = (w & 1) * 64;
  const int srow = l >> 3, sslot = l & 7;

  f32x4 acc[2][4] = {};

  auto stage = [&](int k0, int buf) {
    char* Ab = (char*)lds + buf * 8192;
    char* Bb = (char*)lds + 16384 + buf * 16384;
    #pragma unroll
    for (int i = 0; i < 2; i++) {
      const int row = w * 16 + i * 8 + srow;
      gld16(A + (size_t)(bm + row) * lda + k0 + ((sslot ^ (row & 7)) << 3),
            Ab + w * 2048 + i * 1024);
    }
    #pragma unroll
    for (int i = 0; i < 4; i++) {
      const int row = w * 32 + i * 8 + srow;
      gld16(BT + (size_t)(bn + row) * K + k0 + ((sslot ^ (row & 7)) << 3),
            Bb + w * 4096 + i * 1024);
    }
  };

  stage(0, 0);
  __syncthreads();

  int buf = 0;
  for (int k0 = 0; k0 < K; k0 += 64) {
    if (k0 + 64 < K) stage(k0 + 64, buf ^ 1);   // overlap next-step loads with MFMAs

    const char* Ab = (const char*)lds + buf * 8192;
    const char* Bb = (const char*)lds + 16384 + buf * 16384;
    half8 af[2][2], bfr[2][4];
    #pragma unroll
    for (int mt = 0; mt < 2; mt++) {
      const int row = wr + mt * 16 + ll;
      #pragma unroll
      for (int s = 0; s < 2; s++)
        af[mt][s] = *(const half8*)(Ab + row * 128 + (((4 * s + lg) ^ (row & 7)) << 4));
    }
    #pragma unroll
    for (int nt = 0; nt < 4; nt++) {
      const int row = wc + nt * 16 + ll;
      #pragma unroll
      for (int s = 0; s < 2; s++)
        bfr[s][nt] = *(const half8*)(Bb + row * 128 + (((4 * s + lg) ^ (row & 7)) << 4));
    }
    __builtin_amdgcn_s_setprio(1);
    #pragma unroll
    for (int s = 0; s < 2; s++)
      #pragma unroll
      for (int mt = 0; mt < 2; mt++)
        #pragma unroll
        for (int nt = 0; nt < 4; nt++)
          acc[mt][nt] = __builtin_amdgcn_mfma_f32_16x16x32_f16(af[mt][s], bfr[s][nt], acc[mt][nt], 0, 0, 0);
    __builtin_amdgcn_s_setprio(0);

    __syncthreads();   // drains this step's gld16s; guards buffer reuse
    buf ^= 1;
  }

  // D layout: col = lane&15, row = (lane>>4)*4 + reg
  if constexpr (EPI) {
    const int col0 = bn + wc;
    const int head = col0 >> 6;
    if (head >= 20) {
      // ---- v heads: mix with value-embedding, store TRANSPOSED into vT ----
      const int mloc = head - 20;
      const int bq = bm >> 11;                 // batch (rows 0..2047 -> b=0)
      const int vbm = bq * KVH + mloc;
      const int sl0 = bm - bq * S_LEN;         // tile's local s of row 0
      const float vl = vlam[0];
      #pragma unroll
      for (int mt = 0; mt < 2; mt++) {
        const int s_base = sl0 + wr + mt * 16 + lg * 4;   // local s for r=0
        int   tok[4];
        float vg[4];
        #pragma unroll
        for (int r = 0; r < 4; r++) {
          const size_t grow = (size_t)bq * S_LEN + s_base + r;
          tok[r] = token_ids[grow];
          vg[r]  = veg4[grow * KVH + mloc];
        }
        #pragma unroll
        for (int nt = 0; nt < 4; nt++) {
          const int d = nt * 16 + ll;          // dim within head (col0 == head*64)
          half4 o4;
          #pragma unroll
          for (int r = 0; r < 4; r++) {
            const float e = ve_embed[(size_t)tok[r] * 256 + mloc * 64 + d];
            o4[r] = (_Float16)(vl * acc[mt][nt][r] + vg[r] * e);
          }
          *(half4*)(vT + ((size_t)vbm * 64 + d) * S_LEN + s_base) = o4;
        }
      }
    } else {
      // ---- q/k heads: qk-norm + RoPE (+ q-scale) ----
      const float qs = (head < 16) ? 0.18033688f : 1.0f;  // 1/sqrt(HD)*log2e into q
      #pragma unroll
      for (int mt = 0; mt < 2; mt++) {
        float ss[4];
        #pragma unroll
        for (int r = 0; r < 4; r++)
          ss[r] = acc[mt][0][r] * acc[mt][0][r] + acc[mt][1][r] * acc[mt][1][r]
                + acc[mt][2][r] * acc[mt][2][r] + acc[mt][3][r] * acc[mt][3][r];
        #pragma unroll
        for (int mi = 0; mi < 4; mi++) {
          const int msk = 1 << mi;   // 1,2,4,8: stays within the 16-lane row group
          #pragma unroll
          for (int r = 0; r < 4; r++) ss[r] += __shfl_xor(ss[r], msk);
        }
        #pragma unroll
        for (int r = 0; r < 4; r++) {
          const size_t row = (size_t)bm + wr + mt * 16 + lg * 4 + r;
          const float inv = rsqrtf(ss[r] * (1.0f / 64.0f) + 1e-6f) * qs;
          const float2 cs2 = costab[(row & (S_LEN - 1)) * 16 + ll];
          const float a0 = acc[mt][0][r] * inv, a1 = acc[mt][1][r] * inv;
          C[row * N + col0 +      ll] = (OUT_T)(a0 * cs2.x - a1 * cs2.y);
          C[row * N + col0 + 16 + ll] = (OUT_T)(a1 * cs2.x + a0 * cs2.y);
          C[row * N + col0 + 32 + ll] = (OUT_T)(acc[mt][2][r] * inv);
          C[row * N + col0 + 48 + ll] = (OUT_T)(acc[mt][3][r] * inv);
        }
      }
    }
  } else {
    #pragma unroll
    for (int mt = 0; mt < 2; mt++) {
      #pragma unroll
      for (int r = 0; r < 4; r++) {
        const size_t row = (size_t)bm + wr + mt * 16 + lg * 4 + r;
        #pragma unroll
        for (int nt = 0; nt < 4; nt++) {
          const int col = bn + wc + nt * 16 + ll;
          if constexpr (sizeof(OUT_T) == 2) C[row * N + col] = (OUT_T)(_Float16)acc[mt][nt][r];
          else                              C[row * N + col] = acc[mt][nt][r];
        }
      }
    }
  }
}

// ---------------- MFMA flash attention (causal, GQA), FIXED-MAX, 2q x 2k wave split ----
// 1024 blocks x 256 threads, LPT order, KVBLK=64 dbuf, LDS 40KB.
// Waves split as 2 q-groups x 2 k-halves; fixed max M=11.6 folded into MFMA C-init;
// l via ones-column MFMA; cvt_pkrtz pack; cross-k-half reduction via dead K-buf LDS.
__global__ __launch_bounds__(256) void attn_mfma(
    _Float16* __restrict__ qkv, const _Float16* __restrict__ vT,
    const float* __restrict__ ag)
{
  const int L = blockIdx.x;
  const int qt = 31 - (L >> 5);         // LPT: biggest blocks dispatched first
  const int b = (L >> 4) & 1;
  const int n = L & 15;
  const int m = n >> 2;

  const int t = threadIdx.x, w = t >> 6, l = t & 63;
  const int lg = l >> 4, ll = l & 15;
  const int g  = w & 1;                 // q-group (32 rows)
  const int kh = w >> 1;                // k-half (32 cols of each tile)

  // LDS map (40 KB): [0,16K) = K buf0/1, [16K,32K) = V buf0/1, [32K,40K) = Ps
  __shared__ _Float16 lds[20480];

  const int qbl = qt * 64 + g * 32;     // sequence-local first q row of this wave
  const size_t qrow_g = (size_t)(b * S_LEN) + qbl;

  half8 qa[2][2];
  #pragma unroll
  for (int qf = 0; qf < 2; qf++)
    #pragma unroll
    for (int s = 0; s < 2; s++)
      qa[qf][s] = *(const half8*)(qkv + (qrow_g + qf * 16 + ll) * 1536 + n * 64 + s * 32 + lg * 8);

  float agr[2][4];
  if (kh == 0) {   // only the k-half-0 waves do the final write
    #pragma unroll
    for (int qf = 0; qf < 2; qf++)
      #pragma unroll
      for (int r = 0; r < 4; r++)
        agr[qf][r] = ag[(qrow_g + qf * 16 + lg * 4 + r) * NHEADS + n];
  }

  half8 ones;
  #pragma unroll
  for (int i = 0; i < 8; i++) ones[i] = (_Float16)1.0f;

  f32x4 o[2][4] = {};
  f32x4 ol[2] = {};                     // l via ones-column MFMA, per q-frag

  const int srow = l >> 3, sslot = l & 7;

  auto stage = [&](int kt, int buf) {
    #pragma unroll
    for (int i = 0; i < 2; i++) {
      const int kr = w * 16 + i * 8 + srow;
      const size_t kg = ((size_t)(b * S_LEN + kt * 64 + kr)) * 1536 + 1024 + m * 64
                        + ((sslot ^ (kr & 7)) << 3);
      gld16(qkv + kg, (char*)lds + buf * 8192 + w * 2048 + i * 1024);
      const int vr = w * 16 + i * 8 + srow;
      const size_t vg = ((size_t)((b * KVH + m) * 64 + vr)) * S_LEN + kt * 64
                        + ((sslot ^ (vr & 7)) << 3);
      gld16(vT + vg, (char*)lds + 16384 + buf * 8192 + w * 2048 + i * 1024);
    }
  };

  stage(0, 0);
  __syncthreads();

  for (int kt = 0; kt <= qt; kt++) {
    const int cur = kt & 1;
    if (kt < qt) stage(kt + 1, cur ^ 1);   // hide next tile's latency under compute

    const char* Ksb = (const char*)lds + cur * 8192;
    const char* Vsb = (const char*)lds + 16384 + cur * 8192;
    char* Psb = (char*)lds + 32768;

    // QK^T (swapped), C pre-seeded with the fixed max: sc = K.Q - 11.6.
    // This wave's k-window: [kh*32, kh*32+32). Each kb feeds both q-frags.
    f32x4 sc[2][2];
    #pragma unroll
    for (int qf = 0; qf < 2; qf++)
      #pragma unroll
      for (int kf = 0; kf < 2; kf++) {
        sc[qf][kf][0] = -11.6f; sc[qf][kf][1] = -11.6f;
        sc[qf][kf][2] = -11.6f; sc[qf][kf][3] = -11.6f;
      }
    __builtin_amdgcn_s_setprio(1);
    #pragma unroll
    for (int s = 0; s < 2; s++)
      #pragma unroll
      for (int kf = 0; kf < 2; kf++) {
        const int krow = kh * 32 + kf * 16 + ll;
        const half8 kb = *(const half8*)(Ksb + krow * 128
                          + (((4 * s + lg) ^ (krow & 7)) << 4));
        sc[0][kf] = __builtin_amdgcn_mfma_f32_16x16x32_f16(kb, qa[0][s], sc[0][kf], 0, 0, 0);
        sc[1][kf] = __builtin_amdgcn_mfma_f32_16x16x32_f16(kb, qa[1][s], sc[1][kf], 0, 0, 0);
      }
    __builtin_amdgcn_s_setprio(0);

    if (kt == qt) {   // diagonal tile: causal mask (k > q -> -inf)
      #pragma unroll
      for (int qf = 0; qf < 2; qf++) {
        const int qg = qbl + qf * 16 + ll;
        #pragma unroll
        for (int kf = 0; kf < 2; kf++)
          #pragma unroll
          for (int r = 0; r < 4; r++)
            if (kt * 64 + kh * 32 + kf * 16 + 4 * lg + r > qg) sc[qf][kf][r] = -1e30f;
      }
    }

    // P = exp2(sc); packed f16 cvt into this wave's slots of Ps[64 q][64 k]
    #pragma unroll
    for (int qf = 0; qf < 2; qf++) {
      const int q_loc = g * 32 + qf * 16 + ll;
      #pragma unroll
      for (int kf = 0; kf < 2; kf++) {
        union { fp16x2 h2[2]; half4 h4; } P;
        P.h2[0] = __builtin_amdgcn_cvt_pkrtz(exp2f(sc[qf][kf][0]), exp2f(sc[qf][kf][1]));
        P.h2[1] = __builtin_amdgcn_cvt_pkrtz(exp2f(sc[qf][kf][2]), exp2f(sc[qf][kf][3]));
        const int slot = (4 * kh + 2 * kf + (lg >> 1)) ^ (q_loc & 7);
        *(half4*)(Psb + q_loc * 128 + slot * 16 + (lg & 1) * 8) = P.h4;
      }
    }

    // PV + l-by-ones over this wave's 32-k window (wave-local Ps, in-order per wave)
    __builtin_amdgcn_s_setprio(1);
    {
      half8 pa[2];
      #pragma unroll
      for (int qf = 0; qf < 2; qf++) {
        const int prow = g * 32 + qf * 16 + ll;
        pa[qf] = *(const half8*)(Psb + prow * 128 + (((4 * kh + lg) ^ (prow & 7)) << 4));
      }
      ol[0] = __builtin_amdgcn_mfma_f32_16x16x32_f16(pa[0], ones, ol[0], 0, 0, 0);
      ol[1] = __builtin_amdgcn_mfma_f32_16x16x32_f16(pa[1], ones, ol[1], 0, 0, 0);
      #pragma unroll
      for (int df = 0; df < 4; df++) {
        const int vrow = df * 16 + ll;
        const half8 vb = *(const half8*)(Vsb + vrow * 128
                          + (((4 * kh + lg) ^ (vrow & 7)) << 4));
        o[0][df] = __builtin_amdgcn_mfma_f32_16x16x32_f16(pa[0], vb, o[0][df], 0, 0, 0);
        o[1][df] = __builtin_amdgcn_mfma_f32_16x16x32_f16(pa[1], vb, o[1][df], 0, 0, 0);
      }
    }
    __builtin_amdgcn_s_setprio(0);

    __syncthreads();   // drains this wave's stage issues; guards buffer reuse
  }

  // ---- cross-k-half reduction through the now-dead K/V buffer LDS ----
  // kh=1 waves deposit partial (o, ol); after one barrier kh=0 waves add + write out.
  char* red = (char*)lds;   // [0,16K): o partials as f32[2 g][32 q][64 d]; +16K: ol
  if (kh == 1) {
    #pragma unroll
    for (int qf = 0; qf < 2; qf++) {
      #pragma unroll
      for (int df = 0; df < 4; df++)
        #pragma unroll
        for (int r = 0; r < 4; r++)
          *(float*)(red + g * 8192 + (qf * 16 + lg * 4 + r) * 256 + (df * 16 + ll) * 4)
              = o[qf][df][r];
      if (ll == 0)
        #pragma unroll
        for (int r = 0; r < 4; r++)
          *(float*)(red + 16384 + g * 128 + (qf * 16 + lg * 4 + r) * 4) = ol[qf][r];
    }
  }
  __syncthreads();
  if (kh == 0) {
    #pragma unroll
    for (int qf = 0; qf < 2; qf++)
      #pragma unroll
      for (int r = 0; r < 4; r++) {
        const int qloc32 = qf * 16 + lg * 4 + r;
        const float lsum = ol[qf][r] + *(const float*)(red + 16384 + g * 128 + qloc32 * 4);
        const size_t qrow = qrow_g + qf * 16 + lg * 4 + r;
        const float scale = agr[qf][r] / lsum;
        #pragma unroll
        for (int df = 0; df < 4; df++) {
          const float ov = o[qf][df][r]
              + *(const float*)(red + g * 8192 + qloc32 * 256 + (df * 16 + ll) * 4);
          qkv[qrow * 1536 + n * 64 + df * 16 + ll] = (_Float16)(ov * scale);
        }
      }
  }
}

extern "C" void kernel_launch(void* const* d_in, const int* in_sizes, int n_in,
                              void* d_out, int out_size, void* d_ws, size_t ws_size,
                              hipStream_t stream) {
  const float* x         = (const float*)d_in[0];
  const int*   token_ids = (const int*)d_in[1];
  // d_in[2] = mask (causal, analytic) — unused
  const float* w_q       = (const float*)d_in[3];
  const float* w_k       = (const float*)d_in[4];
  const float* w_v       = (const float*)d_in[5];
  const float* w_o       = (const float*)d_in[6];
  const float* ve_embed  = (const float*)d_in[7];
  const float* vlam      = (const float*)d_in[8];
  const float* velam     = (const float*)d_in[9];
  const float* ve_gate   = (const float*)d_in[10];
  const float* attn_gate = (const float*)d_in[11];
  float* out = (float*)d_out;

  // workspace carve-up (~20.3 MB)
  char* p = (char*)d_ws;
  _Float16* wqkvT = (_Float16*)p; p += (size_t)1536 * 1024 * 2;    // [wq|wk|wv]^T
  _Float16* woT   = (_Float16*)p; p += (size_t)1024 * 1024 * 2;
  _Float16* qkv   = (_Float16*)p; p += (size_t)4096 * 1536 * 2;    // [B*S][q1024|k256|v-dead]
  _Float16* vTb   = (_Float16*)p; p += (size_t)8 * 64 * S_LEN * 2; // [B*M][64][S]
  float*    ag    = (float*)p;    p += (size_t)4096 * NHEADS * 4;
  float*    veg4  = (float*)p;    p += (size_t)4096 * KVH * 4;     // velam*2*sigmoid(..)

  // scratch aliased into d_out (16.8 MB, dead until final GEMM overwrites it):
  // xh = x as f16 at [0, 8.4MB); costab (256 KB) at [12MB, 12.25MB)
  _Float16* xh = (_Float16*)d_out;
  float2* costab = (float2*)((char*)d_out + (size_t)12 * 1024 * 1024);

  dim3 blk(256);
  setup_fused<<<dim3(2048), blk, 0, stream>>>(w_q, w_k, w_v, w_o, x, attn_gate,
                                              ve_gate, velam,
                                              wqkvT, woT, costab, ag, veg4, xh);

  gemm_k<_Float16, true><<<dim3(12, 64), blk, 0, stream>>>(
      xh, wqkvT, qkv, 4096, 1536, 1024, 1024,
      costab, token_ids, ve_embed, veg4, vlam, vTb);

  attn_mfma<<<dim3(1024), blk, 0, stream>>>(qkv, vTb, ag);

  gemm_k<float, false><<<dim3(8, 64), blk, 0, stream>>>(
      qkv, woT, out, 4096, 1024, 1024, 1536,
      nullptr, nullptr, nullptr, nullptr, nullptr, nullptr);
}